// Round 6
// baseline (165.728 us; speedup 1.0000x reference)
//
#include <hip/hip_runtime.h>
#include <math.h>

// Problem constants (B=4, Nin=64, F=64, T=1024, NH=8, FDIM=64, N=512)
#define QSCALE 0.18033688011112042f   // 0.125 * log2(e): softmax scale folded, exp2 domain

typedef __attribute__((ext_vector_type(4))) float  f32x4;
typedef __attribute__((ext_vector_type(2))) float  f32x2;
typedef __attribute__((ext_vector_type(8))) short  bf16x8;   // MFMA A/B frag (8 bf16)
typedef __attribute__((ext_vector_type(4))) short  bf16x4;   // 8B packed store
typedef __attribute__((ext_vector_type(4))) int    i32x4;    // 16B copy

static __device__ __forceinline__ short f2bf(float f) {
    union { float f; unsigned u; } v; v.f = f;
    unsigned r = v.u + 0x7fffu + ((v.u >> 16) & 1u);   // RNE
    return (short)(r >> 16);
}
static __device__ __forceinline__ float bf2f(short s) {
    union { unsigned u; float f; } v; v.u = ((unsigned)(unsigned short)s) << 16;
    return v.f;
}
static __device__ __forceinline__ int pk2bf(float a, float b) {
    return ((int)f2bf(a) & 0xffff) | ((int)f2bf(b) << 16);
}

#define MFMA16(A,B,C) __builtin_amdgcn_mfma_f32_16x16x32_bf16(A, B, C, 0, 0, 0)

// ---------------------------------------------------------------------------
// Kernel 1: xi[b,h,f,t] = sum_c w_in[h,c] * x[b,c,f,t]
// 2 t per thread, f32x2 loads, depth-8 pipeline. Outputs xi_v bf16 and
// xr_t bf16 (LDS transpose). Side jobs (one-shot, no duplication):
//   - w_qk fp32->bf16 with q-scale folded (4 elems/thread, all 512 blocks)
//   - elut_g[h][2048] bias-exp table (64 blocks x 256 thr, 1 entry each)
// Grid (16 tb, 8 fb, 4 b) = 512 blocks.
// ---------------------------------------------------------------------------
__global__ __launch_bounds__(256) void k_proj_in(
    const float* __restrict__ x, const float* __restrict__ w_in,
    const float* __restrict__ wqk, const float* __restrict__ rel_bias,
    short* __restrict__ wqk_b, float* __restrict__ elut_g,
    short* __restrict__ xi_v, short* __restrict__ xr_t)
{
    __shared__ float w_s[512];                    // w_in [8][64]
    __shared__ __align__(16) short tr[64 * 72];   // [t-local][c'=h*8+fy], pad 72
    int tid = threadIdx.x;
    int tx = tid & 31, fy = tid >> 5;
    int tb = blockIdx.x, fb = blockIdx.y, b = blockIdx.z;
    int bflat = (b * 8 + fb) * 16 + tb;           // 0..511

    // fused w_qk conversion: 512 blocks x 256 thr x 4 elems = 524288 (exact)
    {
        int gi = (bflat * 256 + tid) * 4;
        f32x4 wv = *(const f32x4*)&wqk[gi];
        float s = ((gi >> 9) & 64) ? 1.0f : QSCALE;   // q rows scaled, k rows 1
        bf16x4 pk;
        pk.x = f2bf(wv[0] * s); pk.y = f2bf(wv[1] * s);
        pk.z = f2bf(wv[2] * s); pk.w = f2bf(wv[3] * s);
        *(bf16x4*)&wqk_b[gi] = pk;
    }
    // elut_g precompute: 64 blocks x 256 thr -> 8 heads x 2047 entries
    if (bflat < 64) {
        int e = bflat * 256 + tid;                // 0..16383
        int hh = e >> 11, ii = e & 2047;
        if (ii < 2047) {
            int rel = ii - 1023;
            int ret = (rel >= 0) ? 16 : 0;
            int na = rel < 0 ? -rel : rel;
            int idx;
            if (na < 8) idx = ret + na;
            else {
                int vl = 8 + (int)(log2f((float)na * 0.125f) * 2.0f);
                vl = vl > 15 ? 15 : vl;
                idx = ret + vl;
            }
            elut_g[hh * 2048 + ii] = exp2f(rel_bias[idx * 8 + hh] * QSCALE);
        }
    }

    w_s[tid] = w_in[tid & 511];
    w_s[(tid + 256) & 511] = w_in[(tid + 256) & 511];
    __syncthreads();

    int f = fb * 8 + fy;
    int t = tb * 64 + tx * 2;
    float acc[8][2];
    #pragma unroll
    for (int h = 0; h < 8; h++) { acc[h][0] = 0.f; acc[h][1] = 0.f; }

    const float* xp = x + ((size_t)b * 64 * 64 + (size_t)f) * 1024 + t;
    f32x2 buf[8];
    #pragma unroll
    for (int i = 0; i < 8; i++) buf[i] = *(const f32x2*)&xp[(size_t)i * 65536];
    #pragma unroll
    for (int c8 = 0; c8 < 64; c8 += 8) {
        f32x2 cur[8];
        #pragma unroll
        for (int i = 0; i < 8; i++) cur[i] = buf[i];
        if (c8 + 8 < 64) {
            #pragma unroll
            for (int i = 0; i < 8; i++)
                buf[i] = *(const f32x2*)&xp[(size_t)(c8 + 8 + i) * 65536];
        }
        #pragma unroll
        for (int i = 0; i < 8; i++)
            #pragma unroll
            for (int h = 0; h < 8; h++) {
                float wv = w_s[h * 64 + c8 + i];
                acc[h][0] = fmaf(cur[i][0], wv, acc[h][0]);
                acc[h][1] = fmaf(cur[i][1], wv, acc[h][1]);
            }
    }
    // xi_v[b][h][f][t..t+1] (4B packed store)
    #pragma unroll
    for (int h = 0; h < 8; h++)
        *(int*)&xi_v[(((size_t)b * 8 + h) * 64 + f) * 1024 + t] = pk2bf(acc[h][0], acc[h][1]);
    // transpose to xr_t via LDS
    #pragma unroll
    for (int h = 0; h < 8; h++) {
        tr[(tx * 2 + 0) * 72 + h * 8 + fy] = f2bf(acc[h][0]);
        tr[(tx * 2 + 1) * 72 + h * 8 + fy] = f2bf(acc[h][1]);
    }
    __syncthreads();
    int h2 = tid & 7, trow = tid >> 3;            // trow 0..31
    #pragma unroll
    for (int i = 0; i < 2; i++) {
        int t2 = trow + i * 32;
        i32x4 v = *(const i32x4*)&tr[t2 * 72 + h2 * 8];
        *(i32x4*)&xr_t[((size_t)b * 1024 + tb * 64 + t2) * 512 + h2 * 64 + fb * 8] = v;
    }
}

// ---------------------------------------------------------------------------
// Kernel 2: qk[D][t] = sum_c wqk_b[D][c] * xr[c][t]   (per batch)
// Tiles 64D x 64t, BK=128 (4 K-steps, 8 barriers vs 16), 1024 blocks 1D with
// XCD-chunked swizzle. Register double-buffered staging (8 i32x4 in flight).
// Same K-accumulation order as BK=64 version (bit-identical).
// Store qk_t[b][h][t][d2] bf16, d2=D&127.
// ---------------------------------------------------------------------------
__global__ __launch_bounds__(256, 4) void k_qk(
    const short* __restrict__ wqk_b, const short* __restrict__ xr_t,
    short* __restrict__ qk_t)
{
    __shared__ __align__(16) short As[64 * 136];  // [D-local][128 data + 8 pad]
    __shared__ __align__(16) short Bs[64 * 136];  // [t-local][128 data + 8 pad]
    int tid = threadIdx.x;
    int w = tid >> 6, lane = tid & 63;
    int quad = lane >> 4, l16 = lane & 15;
    // bijective XCD-chunked swizzle: 1024 = 8 XCDs x 128
    int bid = blockIdx.x;
    int wg = (bid & 7) * 128 + (bid >> 3);
    int Dt = wg & 15;                             // D0 = Dt*64; h = Dt>>1
    int tb = (wg >> 4) & 15;
    int b  = wg >> 8;
    int t0 = tb * 64;

    f32x4 acc[4];
    #pragma unroll
    for (int tt = 0; tt < 4; tt++) acc[tt] = (f32x4){0.f,0.f,0.f,0.f};

    int s_row = tid >> 2, s_col = (tid & 3) * 32; // 4 thr/row, 64B (32 bf16) each
    const short* Ag = wqk_b + ((size_t)Dt * 64 + s_row) * 512;
    const short* Bg = xr_t + ((size_t)b * 1024 + t0 + s_row) * 512;

    i32x4 ga[4], gb[4];
    #pragma unroll
    for (int i = 0; i < 4; i++) {
        ga[i] = *(const i32x4*)&Ag[s_col + i * 8];
        gb[i] = *(const i32x4*)&Bg[s_col + i * 8];
    }

    for (int kk = 0; kk < 512; kk += 128) {
        #pragma unroll
        for (int i = 0; i < 4; i++) {
            *(i32x4*)&As[s_row * 136 + s_col + i * 8] = ga[i];
            *(i32x4*)&Bs[s_row * 136 + s_col + i * 8] = gb[i];
        }
        __syncthreads();
        if (kk < 384) {
            #pragma unroll
            for (int i = 0; i < 4; i++) {
                ga[i] = *(const i32x4*)&Ag[kk + 128 + s_col + i * 8];
                gb[i] = *(const i32x4*)&Bg[kk + 128 + s_col + i * 8];
            }
        }
        bf16x8 af[4];
        #pragma unroll
        for (int kc = 0; kc < 4; kc++)
            af[kc] = *(const bf16x8*)&As[(w * 16 + l16) * 136 + kc * 32 + quad * 8];
        __builtin_amdgcn_s_setprio(1);
        #pragma unroll
        for (int tt = 0; tt < 4; tt++) {
            #pragma unroll
            for (int kc = 0; kc < 4; kc++) {
                bf16x8 bfr = *(const bf16x8*)&Bs[(tt * 16 + l16) * 136 + kc * 32 + quad * 8];
                acc[tt] = MFMA16(af[kc], bfr, acc[tt]);
            }
        }
        __builtin_amdgcn_s_setprio(0);
        __syncthreads();
    }
    int h = Dt >> 1;
    int d2 = (Dt & 1) * 64 + w * 16 + quad * 4;
    #pragma unroll
    for (int tt = 0; tt < 4; tt++) {
        bf16x4 pk;
        pk.x = f2bf(acc[tt][0]); pk.y = f2bf(acc[tt][1]);
        pk.z = f2bf(acc[tt][2]); pk.w = f2bf(acc[tt][3]);
        int t = t0 + tt * 16 + l16;
        *(bf16x4*)&qk_t[(((size_t)b * 8 + h) * 1024 + t) * 128 + d2] = pk;
    }
}

// ---------------------------------------------------------------------------
// Kernel 3: attention, NO-MAX softmax. mh=2 split, 1024 blocks (4/CU),
// m-tile 64, 8 iters, reg-double-buffered staging, XCD-chunked swizzle.
// elut loaded from precomputed elut_g (no per-block transcendentals).
// o_part stored as bf16 (range-safe; halves partial-O traffic). lsum fp32.
// ---------------------------------------------------------------------------
__global__ __launch_bounds__(256, 4) void k_attn(
    const short* __restrict__ qk_t, const short* __restrict__ xi_v,
    const float* __restrict__ elut_g, short* __restrict__ o_part,
    float* __restrict__ lsum)
{
    __shared__ __align__(16) short Ks[64 * 72];       // [m][64 data + 8 pad]
    __shared__ __align__(16) short Vs[64 * 72];       // [d][64 m + 8 pad]
    __shared__ __align__(16) short Ps[4][16 * 72];    // per wave [n][64 + 8 pad]
    __shared__ float elut[2048];
    int tid = threadIdx.x;
    int w = tid >> 6, lane = tid & 63;
    int quad = lane >> 4, l16 = lane & 15;
    // bijective XCD-chunked swizzle: 1024 = 8 XCDs x 128
    int bid = blockIdx.x;
    int wg = (bid & 7) * 128 + (bid >> 3);
    int nb = wg & 15;
    int mh = (wg >> 4) & 1;
    int bh = wg >> 5;
    int h = bh & 7;
    int n_base = nb * 64;

    for (int i = tid; i < 2047; i += 256)
        elut[i] = elut_g[h * 2048 + i];

    const short* qb = qk_t + (size_t)bh * (1024 * 128);
    const short* vb = xi_v + (size_t)bh * (64 * 1024);

    // Q frags (B-operand): lane holds Q[n = n_base + w*16 + l16][kk*32+quad*8+j]
    bf16x8 qf[2];
    #pragma unroll
    for (int kk = 0; kk < 2; kk++)
        qf[kk] = *(const bf16x8*)&qb[(size_t)(n_base + w * 16 + l16) * 128 + kk * 32 + quad * 8];

    f32x4 acc_o[4];
    #pragma unroll
    for (int dt = 0; dt < 4; dt++) acc_o[dt] = (f32x4){0.f,0.f,0.f,0.f};
    float l_st = 0.f;

    // staging map: 4 threads per row, 2 x 16B each
    int srow = tid >> 2;                // 0..63 (m-local for K, d for V)
    int soff = (tid & 3) * 16;          // 0,16,32,48
    int m0 = mh * 512;
    i32x4 gk[2], gv[2];
    #pragma unroll
    for (int i = 0; i < 2; i++) {
        gk[i] = *(const i32x4*)&qb[(size_t)(m0 + srow) * 128 + 64 + soff + i * 8];
        gv[i] = *(const i32x4*)&vb[(size_t)srow * 1024 + m0 + soff + i * 8];
    }

    __syncthreads();   // elut ready

    #pragma unroll 1
    for (int it = 0; it < 8; it++) {
        *(i32x4*)&Ks[srow * 72 + soff]     = gk[0];
        *(i32x4*)&Ks[srow * 72 + soff + 8] = gk[1];
        *(i32x4*)&Vs[srow * 72 + soff]     = gv[0];
        *(i32x4*)&Vs[srow * 72 + soff + 8] = gv[1];
        __syncthreads();
        // prefetch next tile into registers (overlaps compute below)
        if (it < 7) {
            int m1 = m0 + 64;
            #pragma unroll
            for (int i = 0; i < 2; i++) {
                gk[i] = *(const i32x4*)&qb[(size_t)(m1 + srow) * 128 + 64 + soff + i * 8];
                gv[i] = *(const i32x4*)&vb[(size_t)srow * 1024 + m1 + soff + i * 8];
            }
        }

        // sim^T: A = K (m rows), B = Q (n cols); D[m][n], col n = l16
        f32x4 s[4];
        __builtin_amdgcn_s_setprio(1);
        #pragma unroll
        for (int mt = 0; mt < 4; mt++) {
            bf16x8 kf0 = *(const bf16x8*)&Ks[(mt * 16 + l16) * 72 + quad * 8];
            bf16x8 kf1 = *(const bf16x8*)&Ks[(mt * 16 + l16) * 72 + 32 + quad * 8];
            f32x4 tacc = (f32x4){0.f,0.f,0.f,0.f};
            tacc = MFMA16(kf0, qf[0], tacc);
            tacc = MFMA16(kf1, qf[1], tacc);
            s[mt] = tacc;
        }
        __builtin_amdgcn_s_setprio(0);

        // p = exp2(s) * elut[rel]; accumulate l (per-lane partial)
        int n = n_base + w * 16 + l16;
        #pragma unroll
        for (int mt = 0; mt < 4; mt++) {
            int rel0 = m0 + mt * 16 + quad * 4 - n + 1023;
            #pragma unroll
            for (int j = 0; j < 4; j++) {
                float p = exp2f(s[mt][j]) * elut[rel0 + j];
                s[mt][j] = p;
                l_st += p;
            }
        }
        // pack P into per-wave LDS (C-layout -> A-layout)
        #pragma unroll
        for (int mt = 0; mt < 4; mt++) {
            bf16x4 pk;
            pk.x = f2bf(s[mt][0]); pk.y = f2bf(s[mt][1]);
            pk.z = f2bf(s[mt][2]); pk.w = f2bf(s[mt][3]);
            *(bf16x4*)&Ps[w][l16 * 72 + mt * 16 + quad * 4] = pk;
        }
        // PV: O[n][d] += P[n][m] V[m][d]
        __builtin_amdgcn_s_setprio(1);
        #pragma unroll
        for (int si = 0; si < 2; si++) {
            bf16x8 pf = *(const bf16x8*)&Ps[w][l16 * 72 + si * 32 + quad * 8];
            #pragma unroll
            for (int dt = 0; dt < 4; dt++) {
                bf16x8 vf = *(const bf16x8*)&Vs[(dt * 16 + l16) * 72 + si * 32 + quad * 8];
                acc_o[dt] = MFMA16(pf, vf, acc_o[dt]);
            }
        }
        __builtin_amdgcn_s_setprio(0);
        m0 += 64;
        __syncthreads();
    }
    // store raw O partial (bf16): o_part[mh][bh][d][n]
    #pragma unroll
    for (int dt = 0; dt < 4; dt++) {
        bf16x4 pk;
        pk.x = f2bf(acc_o[dt][0]); pk.y = f2bf(acc_o[dt][1]);
        pk.z = f2bf(acc_o[dt][2]); pk.w = f2bf(acc_o[dt][3]);
        *(bf16x4*)&o_part[(((size_t)mh * 32 + bh) * 64 + dt * 16 + l16) * 1024 + n_base + w * 16 + quad * 4] = pk;
    }
    // store l partial (full column sum after cross-quad reduce)
    l_st += __shfl_xor(l_st, 16);
    l_st += __shfl_xor(l_st, 32);
    if (quad == 0)
        lsum[((size_t)bh * 2 + mh) * 1024 + n_base + w * 16 + l16] = l_st;
}

// ---------------------------------------------------------------------------
// Kernel 4: merge two m-halves + output projection. Vectorized o_part reads
// (bf16x2 int loads, was scalar ushort) + f32x2 lsum. block = (tq, f, b)
// covers out[b][0..63][f][tq*512..+511]; 2 t per thread. Grid (2,64,4).
// out stores: each wave writes 64 x f32x4 = 1KB contiguous per (c,i).
// Arithmetic order identical to r5 (bit-exact).
// ---------------------------------------------------------------------------
__global__ __launch_bounds__(256) void k_proj_out(
    const short* __restrict__ o_part, const float* __restrict__ lsum,
    const float* __restrict__ w_out, float* __restrict__ out)
{
    __shared__ float w_s[512];
    __shared__ float o_s[8][512];
    int tid = threadIdx.x;
    int tq = blockIdx.x, f = blockIdx.y, b = blockIdx.z;
    w_s[tid] = w_out[tid];
    w_s[tid + 256] = w_out[tid + 256];
    int t2 = tq * 512 + tid * 2;
    #pragma unroll
    for (int hh = 0; hh < 8; hh++) {
        int bh = b * 8 + hh;
        f32x2 l0 = *(const f32x2*)&lsum[((size_t)bh * 2 + 0) * 1024 + t2];
        f32x2 l1 = *(const f32x2*)&lsum[((size_t)bh * 2 + 1) * 1024 + t2];
        int o0 = *(const int*)&o_part[((size_t)(0 * 32 + bh) * 64 + f) * 1024 + t2];
        int o1 = *(const int*)&o_part[((size_t)(1 * 32 + bh) * 64 + f) * 1024 + t2];
        f32x2 r;
        r[0] = (bf2f((short)(o0 & 0xffff)) + bf2f((short)(o1 & 0xffff))) / (l0[0] + l1[0]);
        r[1] = (bf2f((short)(o0 >> 16))    + bf2f((short)(o1 >> 16)))    / (l0[1] + l1[1]);
        *(f32x2*)&o_s[hh][tid * 2] = r;
    }
    __syncthreads();
    int tx4 = tid & 63, ty2 = tid >> 6;
    #pragma unroll
    for (int i = 0; i < 2; i++) {
        f32x4 ov[8];
        #pragma unroll
        for (int hh = 0; hh < 8; hh++)
            ov[hh] = *(const f32x4*)&o_s[hh][i * 256 + tx4 * 4];
        #pragma unroll
        for (int j = 0; j < 16; j++) {
            int c = ty2 * 16 + j;
            f32x4 a = (f32x4){0.f,0.f,0.f,0.f};
            #pragma unroll
            for (int hh = 0; hh < 8; hh++) {
                float wv = w_s[c * 8 + hh];
                a[0] = fmaf(ov[hh][0], wv, a[0]);
                a[1] = fmaf(ov[hh][1], wv, a[1]);
                a[2] = fmaf(ov[hh][2], wv, a[2]);
                a[3] = fmaf(ov[hh][3], wv, a[3]);
            }
            *(f32x4*)&out[(((size_t)b * 64 + c) * 64 + f) * 1024 + tq * 512 + i * 256 + tx4 * 4] = a;
        }
    }
}

// ---------------------------------------------------------------------------
extern "C" void kernel_launch(void* const* d_in, const int* in_sizes, int n_in,
                              void* d_out, int out_size, void* d_ws, size_t ws_size,
                              hipStream_t stream)
{
    const float* x        = (const float*)d_in[0];   // [4][64][64][1024]
    const float* w_in     = (const float*)d_in[1];   // [8][64]
    const float* wqk      = (const float*)d_in[2];   // [1024][512]
    const float* w_out    = (const float*)d_in[3];   // [64][8]
    const float* rel_bias = (const float*)d_in[4];   // [32][8]
    float* out = (float*)d_out;                      // [4][64][64][1024]

    char* ws = (char*)d_ws;                          // ~25.3 MB used
    short* wqk_b  = (short*)(ws);                    // 1 MB
    short* xi_v   = (short*)(ws + (size_t)1  * (1 << 20));  // 4 MB
    short* xr_t   = (short*)(ws + (size_t)5  * (1 << 20));  // 4 MB
    short* qk_t   = (short*)(ws + (size_t)9  * (1 << 20));  // 8 MB
    short* o_part = (short*)(ws + (size_t)17 * (1 << 20));  // 8 MB bf16 (2 halves)
    float* lsum   = (float*)(ws + (size_t)25 * (1 << 20));  // 0.25 MB
    float* elut_g = (float*)(ws + (size_t)25 * (1 << 20) + 262144);  // 64 KB

    hipLaunchKernelGGL(k_proj_in,  dim3(16, 8, 4), dim3(256), 0, stream,
                       x, w_in, wqk, rel_bias, wqk_b, elut_g, xi_v, xr_t);
    hipLaunchKernelGGL(k_qk,       dim3(1024),     dim3(256), 0, stream, wqk_b, xr_t, qk_t);
    hipLaunchKernelGGL(k_attn,     dim3(1024),     dim3(256), 0, stream, qk_t, xi_v, elut_g, o_part, lsum);
    hipLaunchKernelGGL(k_proj_out, dim3(2, 64, 4), dim3(256), 0, stream, o_part, lsum, w_out, out);
}

// Round 7
// 156.704 us; speedup vs baseline: 1.0576x; 1.0576x over previous
//
#include <hip/hip_runtime.h>
#include <math.h>

// Problem constants (B=4, Nin=64, F=64, T=1024, NH=8, FDIM=64, N=512)
#define QSCALE 0.18033688011112042f   // 0.125 * log2(e): softmax scale folded, exp2 domain

typedef __attribute__((ext_vector_type(4))) float  f32x4;
typedef __attribute__((ext_vector_type(2))) float  f32x2;
typedef __attribute__((ext_vector_type(8))) short  bf16x8;   // MFMA A/B frag (8 bf16)
typedef __attribute__((ext_vector_type(4))) short  bf16x4;   // 8B packed store
typedef __attribute__((ext_vector_type(4))) int    i32x4;    // 16B copy

static __device__ __forceinline__ short f2bf(float f) {
    union { float f; unsigned u; } v; v.f = f;
    unsigned r = v.u + 0x7fffu + ((v.u >> 16) & 1u);   // RNE
    return (short)(r >> 16);
}
static __device__ __forceinline__ float bf2f(short s) {
    union { unsigned u; float f; } v; v.u = ((unsigned)(unsigned short)s) << 16;
    return v.f;
}
static __device__ __forceinline__ int pk2bf(float a, float b) {
    return ((int)f2bf(a) & 0xffff) | ((int)f2bf(b) << 16);
}

#define MFMA16(A,B,C) __builtin_amdgcn_mfma_f32_16x16x32_bf16(A, B, C, 0, 0, 0)

// ---------------------------------------------------------------------------
// Kernel 1: xi[b,h,f,t] = sum_c w_in[h,c] * x[b,c,f,t]
// 2 t per thread, f32x2 loads, depth-8 pipeline. Outputs xi_v bf16 and
// xr_t bf16 (LDS transpose). Side jobs (one-shot, no duplication):
//   - w_qk fp32->bf16 with q-scale folded (4 elems/thread, all 512 blocks)
//   - elut_g[h][2048] bias-exp table (64 blocks x 256 thr, 1 entry each)
// Grid (16 tb, 8 fb, 4 b) = 512 blocks.
// ---------------------------------------------------------------------------
__global__ __launch_bounds__(256) void k_proj_in(
    const float* __restrict__ x, const float* __restrict__ w_in,
    const float* __restrict__ wqk, const float* __restrict__ rel_bias,
    short* __restrict__ wqk_b, float* __restrict__ elut_g,
    short* __restrict__ xi_v, short* __restrict__ xr_t)
{
    __shared__ float w_s[512];                    // w_in [8][64]
    __shared__ __align__(16) short tr[64 * 72];   // [t-local][c'=h*8+fy], pad 72
    int tid = threadIdx.x;
    int tx = tid & 31, fy = tid >> 5;
    int tb = blockIdx.x, fb = blockIdx.y, b = blockIdx.z;
    int bflat = (b * 8 + fb) * 16 + tb;           // 0..511

    // fused w_qk conversion: 512 blocks x 256 thr x 4 elems = 524288 (exact)
    {
        int gi = (bflat * 256 + tid) * 4;
        f32x4 wv = *(const f32x4*)&wqk[gi];
        float s = ((gi >> 9) & 64) ? 1.0f : QSCALE;   // q rows scaled, k rows 1
        bf16x4 pk;
        pk.x = f2bf(wv[0] * s); pk.y = f2bf(wv[1] * s);
        pk.z = f2bf(wv[2] * s); pk.w = f2bf(wv[3] * s);
        *(bf16x4*)&wqk_b[gi] = pk;
    }
    // elut_g precompute: 64 blocks x 256 thr -> 8 heads x 2047 entries
    if (bflat < 64) {
        int e = bflat * 256 + tid;                // 0..16383
        int hh = e >> 11, ii = e & 2047;
        if (ii < 2047) {
            int rel = ii - 1023;
            int ret = (rel >= 0) ? 16 : 0;
            int na = rel < 0 ? -rel : rel;
            int idx;
            if (na < 8) idx = ret + na;
            else {
                int vl = 8 + (int)(log2f((float)na * 0.125f) * 2.0f);
                vl = vl > 15 ? 15 : vl;
                idx = ret + vl;
            }
            elut_g[hh * 2048 + ii] = exp2f(rel_bias[idx * 8 + hh] * QSCALE);
        }
    }

    w_s[tid] = w_in[tid & 511];
    w_s[(tid + 256) & 511] = w_in[(tid + 256) & 511];
    __syncthreads();

    int f = fb * 8 + fy;
    int t = tb * 64 + tx * 2;
    float acc[8][2];
    #pragma unroll
    for (int h = 0; h < 8; h++) { acc[h][0] = 0.f; acc[h][1] = 0.f; }

    const float* xp = x + ((size_t)b * 64 * 64 + (size_t)f) * 1024 + t;
    f32x2 buf[8];
    #pragma unroll
    for (int i = 0; i < 8; i++) buf[i] = *(const f32x2*)&xp[(size_t)i * 65536];
    #pragma unroll
    for (int c8 = 0; c8 < 64; c8 += 8) {
        f32x2 cur[8];
        #pragma unroll
        for (int i = 0; i < 8; i++) cur[i] = buf[i];
        if (c8 + 8 < 64) {
            #pragma unroll
            for (int i = 0; i < 8; i++)
                buf[i] = *(const f32x2*)&xp[(size_t)(c8 + 8 + i) * 65536];
        }
        #pragma unroll
        for (int i = 0; i < 8; i++)
            #pragma unroll
            for (int h = 0; h < 8; h++) {
                float wv = w_s[h * 64 + c8 + i];
                acc[h][0] = fmaf(cur[i][0], wv, acc[h][0]);
                acc[h][1] = fmaf(cur[i][1], wv, acc[h][1]);
            }
    }
    // xi_v[b][h][f][t..t+1] (4B packed store)
    #pragma unroll
    for (int h = 0; h < 8; h++)
        *(int*)&xi_v[(((size_t)b * 8 + h) * 64 + f) * 1024 + t] = pk2bf(acc[h][0], acc[h][1]);
    // transpose to xr_t via LDS
    #pragma unroll
    for (int h = 0; h < 8; h++) {
        tr[(tx * 2 + 0) * 72 + h * 8 + fy] = f2bf(acc[h][0]);
        tr[(tx * 2 + 1) * 72 + h * 8 + fy] = f2bf(acc[h][1]);
    }
    __syncthreads();
    int h2 = tid & 7, trow = tid >> 3;            // trow 0..31
    #pragma unroll
    for (int i = 0; i < 2; i++) {
        int t2 = trow + i * 32;
        i32x4 v = *(const i32x4*)&tr[t2 * 72 + h2 * 8];
        *(i32x4*)&xr_t[((size_t)b * 1024 + tb * 64 + t2) * 512 + h2 * 64 + fb * 8] = v;
    }
}

// ---------------------------------------------------------------------------
// Kernel 2: qk[D][t] = sum_c wqk_b[D][c] * xr[c][t]   (per batch)
// Tiles 64D x 64t, BK=64, 1024 blocks 1D with XCD-chunked swizzle.
// Register double-buffered staging. Store qk_t[b][h][t][d2] bf16, d2=D&127.
// (BK=128 variant regressed in r6 -- kept at proven BK=64.)
// ---------------------------------------------------------------------------
__global__ __launch_bounds__(256, 4) void k_qk(
    const short* __restrict__ wqk_b, const short* __restrict__ xr_t,
    short* __restrict__ qk_t)
{
    __shared__ __align__(16) short As[64 * 72];   // [D-local][64 data + 8 pad]
    __shared__ __align__(16) short Bs[64 * 72];   // [t-local][64 data + 8 pad]
    int tid = threadIdx.x;
    int w = tid >> 6, lane = tid & 63;
    int quad = lane >> 4, l16 = lane & 15;
    // bijective XCD-chunked swizzle: 1024 = 8 XCDs x 128
    int bid = blockIdx.x;
    int wg = (bid & 7) * 128 + (bid >> 3);
    int Dt = wg & 15;                             // D0 = Dt*64; h = Dt>>1
    int tb = (wg >> 4) & 15;
    int b  = wg >> 8;
    int t0 = tb * 64;

    f32x4 acc[4];
    #pragma unroll
    for (int tt = 0; tt < 4; tt++) acc[tt] = (f32x4){0.f,0.f,0.f,0.f};

    int s_row = tid >> 2, s_col = (tid & 3) * 16;
    const short* Ag = wqk_b + ((size_t)Dt * 64 + s_row) * 512;
    const short* Bg = xr_t + ((size_t)b * 1024 + t0 + s_row) * 512;

    i32x4 ga[2], gb[2];
    #pragma unroll
    for (int i = 0; i < 2; i++) {
        ga[i] = *(const i32x4*)&Ag[s_col + i * 8];
        gb[i] = *(const i32x4*)&Bg[s_col + i * 8];
    }

    for (int kk = 0; kk < 512; kk += 64) {
        *(i32x4*)&As[s_row * 72 + s_col]     = ga[0];
        *(i32x4*)&As[s_row * 72 + s_col + 8] = ga[1];
        *(i32x4*)&Bs[s_row * 72 + s_col]     = gb[0];
        *(i32x4*)&Bs[s_row * 72 + s_col + 8] = gb[1];
        __syncthreads();
        if (kk < 448) {
            #pragma unroll
            for (int i = 0; i < 2; i++) {
                ga[i] = *(const i32x4*)&Ag[kk + 64 + s_col + i * 8];
                gb[i] = *(const i32x4*)&Bg[kk + 64 + s_col + i * 8];
            }
        }
        bf16x8 af[2];
        #pragma unroll
        for (int kc = 0; kc < 2; kc++)
            af[kc] = *(const bf16x8*)&As[(w * 16 + l16) * 72 + kc * 32 + quad * 8];
        __builtin_amdgcn_s_setprio(1);
        #pragma unroll
        for (int tt = 0; tt < 4; tt++) {
            bf16x8 bf0 = *(const bf16x8*)&Bs[(tt * 16 + l16) * 72 + quad * 8];
            bf16x8 bf1 = *(const bf16x8*)&Bs[(tt * 16 + l16) * 72 + 32 + quad * 8];
            acc[tt] = MFMA16(af[0], bf0, acc[tt]);
            acc[tt] = MFMA16(af[1], bf1, acc[tt]);
        }
        __builtin_amdgcn_s_setprio(0);
        __syncthreads();
    }
    int h = Dt >> 1;
    int d2 = (Dt & 1) * 64 + w * 16 + quad * 4;
    #pragma unroll
    for (int tt = 0; tt < 4; tt++) {
        bf16x4 pk;
        pk.x = f2bf(acc[tt][0]); pk.y = f2bf(acc[tt][1]);
        pk.z = f2bf(acc[tt][2]); pk.w = f2bf(acc[tt][3]);
        int t = t0 + tt * 16 + l16;
        *(bf16x4*)&qk_t[(((size_t)b * 8 + h) * 1024 + t) * 128 + d2] = pk;
    }
}

// ---------------------------------------------------------------------------
// Kernel 3: attention, NO-MAX softmax. mh=2 split, 1024 blocks (4/CU),
// m-tile 64, 8 iters, reg-double-buffered staging, XCD-chunked swizzle.
// elut loaded from precomputed elut_g (no per-block transcendentals).
// o_part stored as bf16 (range-safe; halves partial-O traffic). lsum fp32.
// ---------------------------------------------------------------------------
__global__ __launch_bounds__(256, 4) void k_attn(
    const short* __restrict__ qk_t, const short* __restrict__ xi_v,
    const float* __restrict__ elut_g, short* __restrict__ o_part,
    float* __restrict__ lsum)
{
    __shared__ __align__(16) short Ks[64 * 72];       // [m][64 data + 8 pad]
    __shared__ __align__(16) short Vs[64 * 72];       // [d][64 m + 8 pad]
    __shared__ __align__(16) short Ps[4][16 * 72];    // per wave [n][64 + 8 pad]
    __shared__ float elut[2048];
    int tid = threadIdx.x;
    int w = tid >> 6, lane = tid & 63;
    int quad = lane >> 4, l16 = lane & 15;
    // bijective XCD-chunked swizzle: 1024 = 8 XCDs x 128
    int bid = blockIdx.x;
    int wg = (bid & 7) * 128 + (bid >> 3);
    int nb = wg & 15;
    int mh = (wg >> 4) & 1;
    int bh = wg >> 5;
    int h = bh & 7;
    int n_base = nb * 64;

    for (int i = tid; i < 2047; i += 256)
        elut[i] = elut_g[h * 2048 + i];

    const short* qb = qk_t + (size_t)bh * (1024 * 128);
    const short* vb = xi_v + (size_t)bh * (64 * 1024);

    // Q frags (B-operand): lane holds Q[n = n_base + w*16 + l16][kk*32+quad*8+j]
    bf16x8 qf[2];
    #pragma unroll
    for (int kk = 0; kk < 2; kk++)
        qf[kk] = *(const bf16x8*)&qb[(size_t)(n_base + w * 16 + l16) * 128 + kk * 32 + quad * 8];

    f32x4 acc_o[4];
    #pragma unroll
    for (int dt = 0; dt < 4; dt++) acc_o[dt] = (f32x4){0.f,0.f,0.f,0.f};
    float l_st = 0.f;

    // staging map: 4 threads per row, 2 x 16B each
    int srow = tid >> 2;                // 0..63 (m-local for K, d for V)
    int soff = (tid & 3) * 16;          // 0,16,32,48
    int m0 = mh * 512;
    i32x4 gk[2], gv[2];
    #pragma unroll
    for (int i = 0; i < 2; i++) {
        gk[i] = *(const i32x4*)&qb[(size_t)(m0 + srow) * 128 + 64 + soff + i * 8];
        gv[i] = *(const i32x4*)&vb[(size_t)srow * 1024 + m0 + soff + i * 8];
    }

    __syncthreads();   // elut ready

    #pragma unroll 1
    for (int it = 0; it < 8; it++) {
        *(i32x4*)&Ks[srow * 72 + soff]     = gk[0];
        *(i32x4*)&Ks[srow * 72 + soff + 8] = gk[1];
        *(i32x4*)&Vs[srow * 72 + soff]     = gv[0];
        *(i32x4*)&Vs[srow * 72 + soff + 8] = gv[1];
        __syncthreads();
        // prefetch next tile into registers (overlaps compute below)
        if (it < 7) {
            int m1 = m0 + 64;
            #pragma unroll
            for (int i = 0; i < 2; i++) {
                gk[i] = *(const i32x4*)&qb[(size_t)(m1 + srow) * 128 + 64 + soff + i * 8];
                gv[i] = *(const i32x4*)&vb[(size_t)srow * 1024 + m1 + soff + i * 8];
            }
        }

        // sim^T: A = K (m rows), B = Q (n cols); D[m][n], col n = l16
        f32x4 s[4];
        __builtin_amdgcn_s_setprio(1);
        #pragma unroll
        for (int mt = 0; mt < 4; mt++) {
            bf16x8 kf0 = *(const bf16x8*)&Ks[(mt * 16 + l16) * 72 + quad * 8];
            bf16x8 kf1 = *(const bf16x8*)&Ks[(mt * 16 + l16) * 72 + 32 + quad * 8];
            f32x4 tacc = (f32x4){0.f,0.f,0.f,0.f};
            tacc = MFMA16(kf0, qf[0], tacc);
            tacc = MFMA16(kf1, qf[1], tacc);
            s[mt] = tacc;
        }
        __builtin_amdgcn_s_setprio(0);

        // p = exp2(s) * elut[rel]; accumulate l (per-lane partial)
        int n = n_base + w * 16 + l16;
        #pragma unroll
        for (int mt = 0; mt < 4; mt++) {
            int rel0 = m0 + mt * 16 + quad * 4 - n + 1023;
            #pragma unroll
            for (int j = 0; j < 4; j++) {
                float p = exp2f(s[mt][j]) * elut[rel0 + j];
                s[mt][j] = p;
                l_st += p;
            }
        }
        // pack P into per-wave LDS (C-layout -> A-layout)
        #pragma unroll
        for (int mt = 0; mt < 4; mt++) {
            bf16x4 pk;
            pk.x = f2bf(s[mt][0]); pk.y = f2bf(s[mt][1]);
            pk.z = f2bf(s[mt][2]); pk.w = f2bf(s[mt][3]);
            *(bf16x4*)&Ps[w][l16 * 72 + mt * 16 + quad * 4] = pk;
        }
        // PV: O[n][d] += P[n][m] V[m][d]
        __builtin_amdgcn_s_setprio(1);
        #pragma unroll
        for (int si = 0; si < 2; si++) {
            bf16x8 pf = *(const bf16x8*)&Ps[w][l16 * 72 + si * 32 + quad * 8];
            #pragma unroll
            for (int dt = 0; dt < 4; dt++) {
                bf16x8 vf = *(const bf16x8*)&Vs[(dt * 16 + l16) * 72 + si * 32 + quad * 8];
                acc_o[dt] = MFMA16(pf, vf, acc_o[dt]);
            }
        }
        __builtin_amdgcn_s_setprio(0);
        m0 += 64;
        __syncthreads();
    }
    // store raw O partial (bf16): o_part[mh][bh][d][n]
    #pragma unroll
    for (int dt = 0; dt < 4; dt++) {
        bf16x4 pk;
        pk.x = f2bf(acc_o[dt][0]); pk.y = f2bf(acc_o[dt][1]);
        pk.z = f2bf(acc_o[dt][2]); pk.w = f2bf(acc_o[dt][3]);
        *(bf16x4*)&o_part[(((size_t)mh * 32 + bh) * 64 + dt * 16 + l16) * 1024 + n_base + w * 16 + quad * 4] = pk;
    }
    // store l partial (full column sum after cross-quad reduce)
    l_st += __shfl_xor(l_st, 16);
    l_st += __shfl_xor(l_st, 32);
    if (quad == 0)
        lsum[((size_t)bh * 2 + mh) * 1024 + n_base + w * 16 + l16] = l_st;
}

// ---------------------------------------------------------------------------
// Kernel 4: merge two m-halves + output projection, 1KB-coalesced both sides.
// block = (tq, f, b): covers out[b][0..63][f][tq*256..+255]. Grid (4,64,4).
// (r6's 512-block 2t/thread variant regressed -- kept at proven 1024-block.)
// ---------------------------------------------------------------------------
__global__ __launch_bounds__(256) void k_proj_out(
    const short* __restrict__ o_part, const float* __restrict__ lsum,
    const float* __restrict__ w_out, float* __restrict__ out)
{
    __shared__ float w_s[512];
    __shared__ float o_s[8][256];
    int tid = threadIdx.x;
    int tq = blockIdx.x, f = blockIdx.y, b = blockIdx.z;
    w_s[tid] = w_out[tid];
    w_s[tid + 256] = w_out[tid + 256];
    int t = tq * 256 + tid;
    #pragma unroll
    for (int hh = 0; hh < 8; hh++) {
        int bh = b * 8 + hh;
        float l0 = lsum[((size_t)bh * 2 + 0) * 1024 + t];
        float l1 = lsum[((size_t)bh * 2 + 1) * 1024 + t];
        float o0 = bf2f(o_part[((size_t)(0 * 32 + bh) * 64 + f) * 1024 + t]);
        float o1 = bf2f(o_part[((size_t)(1 * 32 + bh) * 64 + f) * 1024 + t]);
        o_s[hh][tid] = (o0 + o1) / (l0 + l1);
    }
    __syncthreads();
    int tx4 = tid & 63, ty2 = tid >> 6;
    f32x4 ov[8];
    #pragma unroll
    for (int hh = 0; hh < 8; hh++)
        ov[hh] = *(const f32x4*)&o_s[hh][tx4 * 4];
    size_t obase = ((size_t)b * 64 * 64 + f) * 1024 + tq * 256 + tx4 * 4;
    #pragma unroll
    for (int j = 0; j < 16; j++) {
        int c = ty2 * 16 + j;
        f32x4 a = (f32x4){0.f,0.f,0.f,0.f};
        #pragma unroll
        for (int hh = 0; hh < 8; hh++) {
            float wv = w_s[c * 8 + hh];
            a[0] = fmaf(ov[hh][0], wv, a[0]);
            a[1] = fmaf(ov[hh][1], wv, a[1]);
            a[2] = fmaf(ov[hh][2], wv, a[2]);
            a[3] = fmaf(ov[hh][3], wv, a[3]);
        }
        *(f32x4*)&out[obase + (size_t)c * 65536] = a;
    }
}

// ---------------------------------------------------------------------------
extern "C" void kernel_launch(void* const* d_in, const int* in_sizes, int n_in,
                              void* d_out, int out_size, void* d_ws, size_t ws_size,
                              hipStream_t stream)
{
    const float* x        = (const float*)d_in[0];   // [4][64][64][1024]
    const float* w_in     = (const float*)d_in[1];   // [8][64]
    const float* wqk      = (const float*)d_in[2];   // [1024][512]
    const float* w_out    = (const float*)d_in[3];   // [64][8]
    const float* rel_bias = (const float*)d_in[4];   // [32][8]
    float* out = (float*)d_out;                      // [4][64][64][1024]

    char* ws = (char*)d_ws;                          // ~25.3 MB used
    short* wqk_b  = (short*)(ws);                    // 1 MB
    short* xi_v   = (short*)(ws + (size_t)1  * (1 << 20));  // 4 MB
    short* xr_t   = (short*)(ws + (size_t)5  * (1 << 20));  // 4 MB
    short* qk_t   = (short*)(ws + (size_t)9  * (1 << 20));  // 8 MB
    short* o_part = (short*)(ws + (size_t)17 * (1 << 20));  // 8 MB bf16 (2 halves)
    float* lsum   = (float*)(ws + (size_t)25 * (1 << 20));  // 0.25 MB
    float* elut_g = (float*)(ws + (size_t)25 * (1 << 20) + 262144);  // 64 KB

    hipLaunchKernelGGL(k_proj_in,  dim3(16, 8, 4), dim3(256), 0, stream,
                       x, w_in, wqk, rel_bias, wqk_b, elut_g, xi_v, xr_t);
    hipLaunchKernelGGL(k_qk,       dim3(1024),     dim3(256), 0, stream, wqk_b, xr_t, qk_t);
    hipLaunchKernelGGL(k_attn,     dim3(1024),     dim3(256), 0, stream, qk_t, xi_v, elut_g, o_part, lsum);
    hipLaunchKernelGGL(k_proj_out, dim3(4, 64, 4), dim3(256), 0, stream, o_part, lsum, w_out, out);
}